// Round 12
// baseline (9965.634 us; speedup 1.0000x reference)
//
#include <hip/hip_runtime.h>
#include <hip/hip_fp16.h>

// ---------------------------------------------------------------------------
// 2-layer LSTM (B=256, T=256, D=128, H=1024) + final Linear(H->128).
// Persistent kernel, one phase per timestep. fp16 MFMA, fp32 accum.
// Weights in LDS (loaded once).
//
// R12: NO L2 INVALIDATION, EVER (main loop). Per phase:
//   1. global flag barrier (fence-free; h-writes are sc1 write-through,
//      drained by s_waitcnt(0) before flag publish)
//   2. per-XCD cooperative copy: stage[xcd] <- {bufA[t&1], bufB[(t+1)&1]}
//      via agent-scope (uncached) reads + PLAIN stores (dirty XCD-local L2)
//   3. per-XCD mini-barrier (32 blocks)
//   4. buffer_inv (CU scope = L1-only invalidate)
//   5. compute reads stage via normal cached loads -> XCD-L2 hits.
// xh/weights/biases stay cached across all phases. One agent fence after
// the loop for the final GEMM (hbF freshness across graph replays).
// ---------------------------------------------------------------------------

#define Bq 256
#define Hq 1024

typedef _Float16 half8 __attribute__((ext_vector_type(8)));
typedef float    floatx4 __attribute__((ext_vector_type(4)));

#define N_W1 8388608LL   // 128 cb * 65536  ([ks64][kb4][n2][jj16][e8])
#define N_W0 4718592LL   // 128 cb * 36864  ([ks36][kb4][n2][jj16][e8])
#define N_XH 8388608LL   // T*B*D
#define N_H  262144LL    // B*H
#define BH   262144

// ws byte offsets
#define OFF_W1 0LL
#define OFF_W0 16777216LL
#define OFF_XH 26214400LL
#define OFF_BA 42991616LL
#define OFF_BB 44040192LL
#define OFF_HF 45088768LL
#define OFF_SY 46137344LL
#define OFF_ST 46139392LL            // 8 XCDs x 1 MiB stage
#define REQ_WS 54528000LL            // OFF_ST + 8*1048576

// ---------------------------------------------------------------------------
__global__ void ws_sentinel_kernel(float* __restrict__ out, int n, float v)
{
    int i = blockIdx.x * blockDim.x + threadIdx.x;
    if (i < n) out[i] = v;
}

// ---------------------------------------------------------------------------
__global__ void prep_kernel(const float* __restrict__ x, const float* __restrict__ h0,
                            const float* __restrict__ Wih0, const float* __restrict__ Whh0,
                            const float* __restrict__ Wih1, const float* __restrict__ Whh1,
                            _Float16* __restrict__ w1p, _Float16* __restrict__ w0p,
                            _Float16* __restrict__ xh,
                            _Float16* __restrict__ bufA, _Float16* __restrict__ bufB,
                            unsigned* __restrict__ sync)
{
    long long gid = (long long)blockIdx.x * blockDim.x + threadIdx.x;
    if (gid < 512) sync[gid] = 0u;   // [0..255] global flags, [256..511] xcd flags

    if (gid < N_W1) {
        // [cb][ks][kb][n][jj][e]; gate-col row = (2n + jj>>3)*1024 + cb*8 + (jj&7)
        long long i = gid;
        int e  = (int)(i & 7);
        int jj = (int)((i >> 3) & 15);
        int n  = (int)((i >> 7) & 1);
        int kb = (int)((i >> 8) & 3);
        int ks = (int)((i >> 10) & 63);
        int cb = (int)(i >> 16);
        int row = (2 * n + (jj >> 3)) * 1024 + cb * 8 + (jj & 7);
        int k = ks * 32 + kb * 8 + e;
        float v = (k < 1024) ? Wih1[(size_t)row * 1024 + k]
                             : Whh1[(size_t)row * 1024 + (k - 1024)];
        w1p[i] = (_Float16)v;
    } else if (gid < N_W1 + N_W0) {
        long long i = gid - N_W1;
        int cb = (int)(i / 36864LL);
        int r  = (int)(i - (long long)cb * 36864LL);
        int ks = r >> 10;
        int kb = (r >> 8) & 3;
        int n  = (r >> 7) & 1;
        int jj = (r >> 3) & 15;
        int e  = r & 7;
        int row = (2 * n + (jj >> 3)) * 1024 + cb * 8 + (jj & 7);
        int k = ks * 32 + kb * 8 + e;
        float v = (k < 128) ? Wih0[(size_t)row * 128 + k]
                            : Whh0[(size_t)row * 1024 + (k - 128)];
        w0p[i] = (_Float16)v;
    } else if (gid < N_W1 + N_W0 + N_XH) {
        long long i = gid - N_W1 - N_W0;
        // xh[t][b][d] = x[b][t][d]
        int d = (int)(i & 127);
        int b = (int)((i >> 7) & 255);
        int t = (int)(i >> 15);
        xh[i] = (_Float16)x[((size_t)b * 256 + t) * 128 + d];
    } else if (gid < N_W1 + N_W0 + N_XH + N_H) {
        long long i = gid - N_W1 - N_W0 - N_XH;
        _Float16 v = (_Float16)h0[i];
        bufA[BH + i] = v;   // h_a(-1) parity 1
        bufB[BH + i] = v;   // h_b(-1) parity 1
    }
}

// ---------------------------------------------------------------------------
// Global flag-array barrier, fence-free (data freshness handled by the
// uncached copy reads downstream).
__device__ __forceinline__ void gridbar(unsigned* flags, int bid, unsigned target)
{
    __builtin_amdgcn_s_waitcnt(0);     // own wt stores at coherence point
    __syncthreads();
    if (threadIdx.x == 0)
        __hip_atomic_store(flags + bid, target, __ATOMIC_RELAXED,
                           __HIP_MEMORY_SCOPE_AGENT);
    if (threadIdx.x < 256) {
        int guard = 0;
        while (__hip_atomic_load(flags + threadIdx.x, __ATOMIC_RELAXED,
                                 __HIP_MEMORY_SCOPE_AGENT) < target) {
            __builtin_amdgcn_s_sleep(1);
            if (++guard > (1 << 18)) break;
        }
    }
    __syncthreads();
}

// Per-XCD mini-barrier (32 blocks). Stage plain-stores drained by
// s_waitcnt(0) -> visible in the shared XCD L2 before flag publish.
__device__ __forceinline__ void xcdbar(unsigned* xf, int slot, unsigned target)
{
    __builtin_amdgcn_s_waitcnt(0);
    __syncthreads();
    if (threadIdx.x == 0)
        __hip_atomic_store(xf + slot, target, __ATOMIC_RELAXED,
                           __HIP_MEMORY_SCOPE_AGENT);
    if (threadIdx.x < 32) {
        int guard = 0;
        while (__hip_atomic_load(xf + threadIdx.x, __ATOMIC_RELAXED,
                                 __HIP_MEMORY_SCOPE_AGENT) < target) {
            __builtin_amdgcn_s_sleep(1);
            if (++guard > (1 << 18)) break;
        }
    }
    __syncthreads();
}

// 16B load at the coherence point (bypasses L1+L2)
__device__ __forceinline__ half8 ldIF16(const _Float16* p)
{
    union { unsigned long long u[2]; half8 h; } cv;
    cv.u[0] = __hip_atomic_load((const unsigned long long*)p,
                                __ATOMIC_RELAXED, __HIP_MEMORY_SCOPE_AGENT);
    cv.u[1] = __hip_atomic_load((const unsigned long long*)p + 1,
                                __ATOMIC_RELAXED, __HIP_MEMORY_SCOPE_AGENT);
    return cv.h;
}

#define MFMA16(A, Bv, C) __builtin_amdgcn_mfma_f32_16x16x32_f16((A), (Bv), (C), 0, 0, 0)

// one k-step (K=32): 2 A-frags (cached), 2 B-frags (LDS), 4 MFMAs
#define KS1(AP_, MF1OFF_) do {                                      \
    half8 a0 = *(const half8*)(AP_);                                \
    half8 a1 = *(const half8*)((AP_) + (MF1OFF_));                  \
    half8 b0 = *(const half8*)(bp);                                 \
    half8 b1 = *(const half8*)(bp + 128);                           \
    acc[0][0] = MFMA16(a0, b0, acc[0][0]);                          \
    acc[0][1] = MFMA16(a0, b1, acc[0][1]);                          \
    acc[1][0] = MFMA16(a1, b0, acc[1][0]);                          \
    acc[1][1] = MFMA16(a1, b1, acc[1][1]);                          \
} while (0)

__global__ void __launch_bounds__(512)
lstm_main(const _Float16* __restrict__ w1p, const _Float16* __restrict__ w0p,
          const _Float16* __restrict__ xh,
          _Float16* __restrict__ bufA, _Float16* __restrict__ bufB,
          _Float16* __restrict__ stage,
          float* __restrict__ hbF,
          const float* __restrict__ c0,
          const float* __restrict__ bih0, const float* __restrict__ bhh0,
          const float* __restrict__ bih1, const float* __restrict__ bhh1,
          const float* __restrict__ Wout, const float* __restrict__ bout,
          float* __restrict__ out, unsigned* __restrict__ sync)
{
    __shared__ _Float16 wlds[65536];   // 128 KiB

    const int tid  = threadIdx.x;
    const int lane = tid & 63;
    const int w    = tid >> 6;           // 0..7
    const int bid  = blockIdx.x;
    const int xcd  = bid & 7;            // empirically XCD id (m09/m157)
    const int slot = bid >> 3;           // 0..31 within XCD
    const int isL1 = ((slot & 1) == 0);  // 16 L1 + 16 L0 blocks per XCD
    const int cb   = xcd * 16 + (slot >> 1);   // 0..127 column-block id
    const int jbase = cb * 8;
    const int jj = lane & 15;
    const int kb = lane >> 4;            // 0..3
    const int jh = jj & 7;
    const int lo = (jj < 8);
    const int rowbase = w * 32;          // wave's 32 batch rows

    _Float16* stgA = stage + (size_t)xcd * 524288;        // 512 KiB halves
    _Float16* stgB = stgA + 262144;
    unsigned* xf   = sync + 256 + xcd * 32;

    // ---- load this block's weights into LDS (once) ----
    {
        const _Float16* src = isL1 ? (w1p + (size_t)cb * 65536)
                                   : (w0p + (size_t)cb * 36864);
        const int nch = isL1 ? 8192 : 4608;   // 16B chunks
        for (int i = tid; i < nch; i += 512)
            *(half8*)&wlds[(size_t)i * 8] = *(const half8*)&src[(size_t)i * 8];
    }
    __syncthreads();

    // ---- biases + cell-state init ----
    const float* bi  = isL1 ? bih1 : bih0;
    const float* bhp = isL1 ? bhh1 : bhh0;
    float bias[4];
#pragma unroll
    for (int g = 0; g < 4; ++g)
        bias[g] = bi[g * 1024 + jbase + jh] + bhp[g * 1024 + jbase + jh];

    float cc[2][4];
#pragma unroll
    for (int mf = 0; mf < 2; ++mf)
#pragma unroll
        for (int r = 0; r < 4; ++r)
            cc[mf][r] = c0[(size_t)(rowbase + mf * 16 + kb * 4 + r) * Hq + jbase + jh];

    floatx4 acc[2][2];

    for (int t = -1; t <= 255; ++t) {
        if (t >= 0) {
            // ---- per-XCD cooperative stage copy (1 MiB) ----
            {
                const _Float16* srcA = bufA + (size_t)(t & 1) * BH;
                const _Float16* srcB = bufB + (size_t)((t + 1) & 1) * BH;
                int xt = slot * 512 + tid;               // 0..16383
#pragma unroll
                for (int k2 = 0; k2 < 2; ++k2) {
                    int idx = xt + k2 * 16384;           // 16B-chunk index
                    half8 va = ldIF16(srcA + (size_t)idx * 8);
                    half8 vb = ldIF16(srcB + (size_t)idx * 8);
                    *(half8*)(stgA + (size_t)idx * 8) = va;
                    *(half8*)(stgB + (size_t)idx * 8) = vb;
                }
            }
            xcdbar(xf, slot, (unsigned)(t + 1));
            asm volatile("buffer_inv" ::: "memory");     // L1-only invalidate
            __syncthreads();

            const int active = isL1 ? 1 : (t < 255);
            if (active) {
#pragma unroll
                for (int mf = 0; mf < 2; ++mf)
#pragma unroll
                    for (int n = 0; n < 2; ++n)
                        acc[mf][n] = (floatx4){0.f, 0.f, 0.f, 0.f};

                const _Float16* bp = wlds + kb * 256 + jj * 8;

                if (isL1) {
                    // gates1(t) = h_a(t)@Wih1^T + h_b(t-1)@Whh1^T
                    const _Float16* ap = stgA + (size_t)(rowbase + jj) * Hq + kb * 8;
#pragma unroll 4
                    for (int ks = 0; ks < 32; ++ks) { KS1(ap, 16 * Hq); ap += 32; bp += 1024; }
                    ap = stgB + (size_t)(rowbase + jj) * Hq + kb * 8;
#pragma unroll 4
                    for (int ks = 0; ks < 32; ++ks) { KS1(ap, 16 * Hq); ap += 32; bp += 1024; }
                } else {
                    // gates0(t+1) = x(t+1)@Wih0^T + h_a(t)@Whh0^T
                    const _Float16* ap = xh + (size_t)(t + 1) * (Bq * 128)
                                       + (size_t)(rowbase + jj) * 128 + kb * 8;
#pragma unroll
                    for (int ks = 0; ks < 4; ++ks)  { KS1(ap, 16 * 128); ap += 32; bp += 1024; }
                    ap = stgA + (size_t)(rowbase + jj) * Hq + kb * 8;
#pragma unroll 4
                    for (int ks = 0; ks < 32; ++ks) { KS1(ap, 16 * Hq); ap += 32; bp += 1024; }
                }

                // ---- elementwise + h write-through stores ----
                _Float16* hb = isL1 ? (bufB + (size_t)(t & 1) * BH)
                                    : (bufA + (size_t)((t + 1) & 1) * BH);
                unsigned* hb32 = (unsigned*)hb;
#pragma unroll
                for (int mf = 0; mf < 2; ++mf) {
#pragma unroll
                    for (int r = 0; r < 4; ++r) {
                        float o0 = acc[mf][0][r];       // lo: i, hi: f
                        float o1 = acc[mf][1][r];       // lo: g, hi: o
                        float p0 = __shfl_xor(o0, 8);
                        float p1 = __shfl_xor(o1, 8);
                        float gi = (lo ? o0 : p0) + bias[0];
                        float gf = (lo ? p0 : o0) + bias[1];
                        float gg = (lo ? o1 : p1) + bias[2];
                        float go = (lo ? p1 : o1) + bias[3];
                        float ii = 1.f / (1.f + expf(-gi));
                        float ff = 1.f / (1.f + expf(-gf));
                        float gt = tanhf(gg);
                        float oo = 1.f / (1.f + expf(-go));
                        float cn = ff * cc[mf][r] + ii * gt;
                        cc[mf][r] = cn;
                        float hn = oo * tanhf(cn);

                        union { _Float16 f; unsigned short u; } cv;
                        cv.f = (_Float16)hn;
                        int prt = __shfl_xor((int)cv.u, 1);
                        int row = rowbase + mf * 16 + kb * 4 + r;
                        if (lo && ((jh & 1) == 0)) {
                            unsigned word = (unsigned)cv.u | ((unsigned)prt << 16);
                            __hip_atomic_store(hb32 + (((size_t)row * Hq + jbase + jh) >> 1),
                                               word, __ATOMIC_RELAXED,
                                               __HIP_MEMORY_SCOPE_AGENT);
                        }
                        if (lo && isL1 && t == 255)
                            __hip_atomic_store(hbF + (size_t)row * Hq + jbase + jh,
                                               hn, __ATOMIC_RELAXED,
                                               __HIP_MEMORY_SCOPE_AGENT);
                    }
                }
            }
        }

        gridbar(sync, bid, (unsigned)(t + 2));
    }

    // one-time agent acquire: hbF fresh for cached reads (graph replays)
    if (threadIdx.x < 64)
        __builtin_amdgcn_fence(__ATOMIC_ACQUIRE, "agent");
    __syncthreads();

    // ---- final: out[b][o] = b_out[o] + sum_k hbF[b][k] * Wout[o][k] ----
    int gid = bid * 512 + tid;
    if (gid < Bq * 128) {
        int b = gid >> 7, o = gid & 127;
        const floatx4* hr = (const floatx4*)(hbF + (size_t)b * Hq);
        const floatx4* wr = (const floatx4*)(Wout + (size_t)o * Hq);
        float s = bout[o];
#pragma unroll 4
        for (int k = 0; k < Hq / 4; ++k) {
            floatx4 hv = hr[k], wv = wr[k];
            s += hv[0] * wv[0] + hv[1] * wv[1] + hv[2] * wv[2] + hv[3] * wv[3];
        }
        out[gid] = s;
    }
}

// ---------------------------------------------------------------------------
extern "C" void kernel_launch(void* const* d_in, const int* in_sizes, int n_in,
                              void* d_out, int out_size, void* d_ws, size_t ws_size,
                              hipStream_t stream)
{
    (void)in_sizes; (void)n_in;
    float* out = (float*)d_out;

    if (ws_size < (size_t)REQ_WS) {
        float v = -(float)(ws_size >> 20);
        hipLaunchKernelGGL(ws_sentinel_kernel, dim3((out_size + 255) / 256), dim3(256),
                           0, stream, out, out_size, v);
        return;
    }

    const float* x    = (const float*)d_in[0];
    const float* h0   = (const float*)d_in[1];
    const float* c0   = (const float*)d_in[2];
    const float* Wih0 = (const float*)d_in[3];
    const float* Whh0 = (const float*)d_in[4];
    const float* bih0 = (const float*)d_in[5];
    const float* bhh0 = (const float*)d_in[6];
    const float* Wih1 = (const float*)d_in[7];
    const float* Whh1 = (const float*)d_in[8];
    const float* bih1 = (const float*)d_in[9];
    const float* bhh1 = (const float*)d_in[10];
    const float* Wout = (const float*)d_in[11];
    const float* bout = (const float*)d_in[12];

    char* ws = (char*)d_ws;
    _Float16* w1p  = (_Float16*)(ws + OFF_W1);
    _Float16* w0p  = (_Float16*)(ws + OFF_W0);
    _Float16* xh   = (_Float16*)(ws + OFF_XH);
    _Float16* bufA = (_Float16*)(ws + OFF_BA);
    _Float16* bufB = (_Float16*)(ws + OFF_BB);
    float*    hbF  = (float*)   (ws + OFF_HF);
    unsigned* sync = (unsigned*)(ws + OFF_SY);
    _Float16* stg  = (_Float16*)(ws + OFF_ST);

    long long total = N_W1 + N_W0 + N_XH + N_H;   // 21,757,952 = 84992*256
    hipLaunchKernelGGL(prep_kernel, dim3((unsigned)(total / 256)), dim3(256), 0, stream,
                       x, h0, Wih0, Whh0, Wih1, Whh1, w1p, w0p, xh, bufA, bufB, sync);

    hipLaunchKernelGGL(lstm_main, dim3(256), dim3(512), 0, stream,
                       w1p, w0p, xh, bufA, bufB, stg, hbF, c0,
                       bih0, bhh0, bih1, bhh1, Wout, bout, out, sync);
}

// Round 13
// 9673.739 us; speedup vs baseline: 1.0302x; 1.0302x over previous
//
#include <hip/hip_runtime.h>
#include <hip/hip_fp16.h>

// ---------------------------------------------------------------------------
// 2-layer LSTM (B=256, T=256, D=128, H=1024) + final Linear(H->128).
// Persistent kernel, one phase per timestep, flag-array grid barrier +
// per-phase per-CU acquire fence (R9 data plane, byte-identical).
//
// R13: INLINE-ASM SOFTWARE-PIPELINED A-LOADS. The K-loop is a ring-8
// pipeline: global_load_dwordx4 pairs issued via asm volatile into a
// half8 bf[8][2] register ring, consumed under counted s_waitcnt vmcnt(14)
// + sched_barrier(0); tail drains 14->0. 16 load-instructions (16 KB) in
// flight per wave vs the compiler's ~2-4 -> the 1 MB/block/phase A-stream
// becomes BW-bound instead of latency-serialized (R11's C++ attempt was
// sunk by the compiler: VGPR_Count stayed 92).
// ---------------------------------------------------------------------------

#define Bq 256
#define Hq 1024

typedef _Float16 half8 __attribute__((ext_vector_type(8)));
typedef float    floatx4 __attribute__((ext_vector_type(4)));

#define N_W1 8388608LL   // 128 cb * 65536  ([ks64][kb4][n2][jj16][e8])
#define N_W0 4718592LL   // 128 cb * 36864  ([ks36][kb4][n2][jj16][e8])
#define N_XH 8388608LL   // T*B*D
#define N_H  262144LL    // B*H
#define BH   262144

// ws byte offsets
#define OFF_W1 0LL
#define OFF_W0 16777216LL
#define OFF_XH 26214400LL
#define OFF_BA 42991616LL
#define OFF_BB 44040192LL
#define OFF_HF 45088768LL
#define OFF_SY 46137344LL
#define REQ_WS 46139392LL   // OFF_SY + 2048

// ---------------------------------------------------------------------------
__global__ void ws_sentinel_kernel(float* __restrict__ out, int n, float v)
{
    int i = blockIdx.x * blockDim.x + threadIdx.x;
    if (i < n) out[i] = v;
}

// ---------------------------------------------------------------------------
__global__ void prep_kernel(const float* __restrict__ x, const float* __restrict__ h0,
                            const float* __restrict__ Wih0, const float* __restrict__ Whh0,
                            const float* __restrict__ Wih1, const float* __restrict__ Whh1,
                            _Float16* __restrict__ w1p, _Float16* __restrict__ w0p,
                            _Float16* __restrict__ xh,
                            _Float16* __restrict__ bufA, _Float16* __restrict__ bufB,
                            unsigned* __restrict__ sync)
{
    long long gid = (long long)blockIdx.x * blockDim.x + threadIdx.x;
    if (gid < 512) sync[gid] = 0u;   // 256 arrival flags (monotonic) + spare

    if (gid < N_W1) {
        // [cb][ks][kb][n][jj][e]; gate-col row = (2n + jj>>3)*1024 + cb*8 + (jj&7)
        long long i = gid;
        int e  = (int)(i & 7);
        int jj = (int)((i >> 3) & 15);
        int n  = (int)((i >> 7) & 1);
        int kb = (int)((i >> 8) & 3);
        int ks = (int)((i >> 10) & 63);
        int cb = (int)(i >> 16);
        int row = (2 * n + (jj >> 3)) * 1024 + cb * 8 + (jj & 7);
        int k = ks * 32 + kb * 8 + e;
        float v = (k < 1024) ? Wih1[(size_t)row * 1024 + k]
                             : Whh1[(size_t)row * 1024 + (k - 1024)];
        w1p[i] = (_Float16)v;
    } else if (gid < N_W1 + N_W0) {
        long long i = gid - N_W1;
        int cb = (int)(i / 36864LL);
        int r  = (int)(i - (long long)cb * 36864LL);
        int ks = r >> 10;
        int kb = (r >> 8) & 3;
        int n  = (r >> 7) & 1;
        int jj = (r >> 3) & 15;
        int e  = r & 7;
        int row = (2 * n + (jj >> 3)) * 1024 + cb * 8 + (jj & 7);
        int k = ks * 32 + kb * 8 + e;
        float v = (k < 128) ? Wih0[(size_t)row * 128 + k]
                            : Whh0[(size_t)row * 1024 + (k - 128)];
        w0p[i] = (_Float16)v;
    } else if (gid < N_W1 + N_W0 + N_XH) {
        long long i = gid - N_W1 - N_W0;
        // xh[t][b][d] = x[b][t][d]
        int d = (int)(i & 127);
        int b = (int)((i >> 7) & 255);
        int t = (int)(i >> 15);
        xh[i] = (_Float16)x[((size_t)b * 256 + t) * 128 + d];
    } else if (gid < N_W1 + N_W0 + N_XH + N_H) {
        long long i = gid - N_W1 - N_W0 - N_XH;
        _Float16 v = (_Float16)h0[i];
        bufA[BH + i] = v;   // h_a(-1) parity 1
        bufB[BH + i] = v;   // h_b(-1) parity 1
    }
}

// ---------------------------------------------------------------------------
// Parallel flag-array grid barrier (identical to R9).
__device__ __forceinline__ void gridbar(unsigned* flags, int bid, unsigned target)
{
    __builtin_amdgcn_s_waitcnt(0);     // own write-through stores drained
    __syncthreads();
    if (threadIdx.x == 0)
        __hip_atomic_store(flags + bid, target, __ATOMIC_RELAXED,
                           __HIP_MEMORY_SCOPE_AGENT);
    if (threadIdx.x < 256) {
        int guard = 0;
        while (__hip_atomic_load(flags + threadIdx.x, __ATOMIC_RELAXED,
                                 __HIP_MEMORY_SCOPE_AGENT) < target) {
            __builtin_amdgcn_s_sleep(1);
            if (++guard > (1 << 18)) break;        // safety: wrong, not wedged
        }
    }
    __syncthreads();
    if (threadIdx.x < 64)                           // one inv per CU (L1+L2)
        __builtin_amdgcn_fence(__ATOMIC_ACQUIRE, "agent");
    __syncthreads();
}

#define MFMA16(A, Bv, C) __builtin_amdgcn_mfma_f32_16x16x32_f16((A), (Bv), (C), 0, 0, 0)

// ---- inline-asm pipelined K-step machinery --------------------------------
// Issue a pair of 16B loads into ring slot I (asm -> compiler cannot sink).
#define PISSUE(I, P0, P1)                                           \
    asm volatile("global_load_dwordx4 %0, %2, off\n\t"              \
                 "global_load_dwordx4 %1, %3, off"                  \
                 : "=&v"(bf[I][0]), "=&v"(bf[I][1])                 \
                 : "v"(P0), "v"(P1) : "memory")

// Pipelined step: W ds_reads first (overlap prev MFMAs), then counted
// vmcnt wait + sched_barrier (rule #18), 4 MFMAs, then re-issue slot I.
#define PSTEP14(I, P0, P1) do {                                     \
    half8 b0 = *(const half8*)(bp);                                 \
    half8 b1 = *(const half8*)(bp + 128);                           \
    asm volatile("s_waitcnt vmcnt(14)" ::: "memory");               \
    __builtin_amdgcn_sched_barrier(0);                              \
    acc[0][0] = MFMA16(bf[I][0], b0, acc[0][0]);                    \
    acc[0][1] = MFMA16(bf[I][0], b1, acc[0][1]);                    \
    acc[1][0] = MFMA16(bf[I][1], b0, acc[1][0]);                    \
    acc[1][1] = MFMA16(bf[I][1], b1, acc[1][1]);                    \
    bp += 1024;                                                     \
    PISSUE(I, P0, P1);                                              \
} while (0)

// Drain step (no re-issue), literal wait count NLIT.
#define PSTEPW(I, NLIT) do {                                        \
    half8 b0 = *(const half8*)(bp);                                 \
    half8 b1 = *(const half8*)(bp + 128);                           \
    asm volatile("s_waitcnt vmcnt(" #NLIT ")" ::: "memory");        \
    __builtin_amdgcn_sched_barrier(0);                              \
    acc[0][0] = MFMA16(bf[I][0], b0, acc[0][0]);                    \
    acc[0][1] = MFMA16(bf[I][0], b1, acc[0][1]);                    \
    acc[1][0] = MFMA16(bf[I][1], b0, acc[1][0]);                    \
    acc[1][1] = MFMA16(bf[I][1], b1, acc[1][1]);                    \
    bp += 1024;                                                     \
} while (0)

__global__ void __launch_bounds__(512)
lstm_main(const _Float16* __restrict__ w1p, const _Float16* __restrict__ w0p,
          const _Float16* __restrict__ xh,
          _Float16* __restrict__ bufA, _Float16* __restrict__ bufB,
          float* __restrict__ hbF,
          const float* __restrict__ c0,
          const float* __restrict__ bih0, const float* __restrict__ bhh0,
          const float* __restrict__ bih1, const float* __restrict__ bhh1,
          const float* __restrict__ Wout, const float* __restrict__ bout,
          float* __restrict__ out, unsigned* __restrict__ sync)
{
    __shared__ _Float16 wlds[65536];   // 128 KiB

    const int tid  = threadIdx.x;
    const int lane = tid & 63;
    const int w    = tid >> 6;           // 0..7
    const int bid  = blockIdx.x;
    const int xcd  = bid & 7;
    const int slot = bid >> 3;           // 0..31
    const int isL1 = ((slot & 1) == 0);  // 16 L1 + 16 L0 blocks per XCD
    const int cb   = xcd * 16 + (slot >> 1);   // 0..127 column-block id
    const int jbase = cb * 8;
    const int jj = lane & 15;
    const int kb = lane >> 4;            // 0..3
    const int jh = jj & 7;
    const int lo = (jj < 8);
    const int rowbase = w * 32;          // wave's 32 batch rows

    // ---- load this block's weights into LDS (once) ----
    {
        const _Float16* src = isL1 ? (w1p + (size_t)cb * 65536)
                                   : (w0p + (size_t)cb * 36864);
        const int nch = isL1 ? 8192 : 4608;   // 16B chunks
        for (int i = tid; i < nch; i += 512)
            *(half8*)&wlds[(size_t)i * 8] = *(const half8*)&src[(size_t)i * 8];
    }
    __syncthreads();

    // ---- biases + cell-state init ----
    const float* bi  = isL1 ? bih1 : bih0;
    const float* bhp = isL1 ? bhh1 : bhh0;
    float bias[4];
#pragma unroll
    for (int g = 0; g < 4; ++g)
        bias[g] = bi[g * 1024 + jbase + jh] + bhp[g * 1024 + jbase + jh];

    float cc[2][4];
#pragma unroll
    for (int mf = 0; mf < 2; ++mf)
#pragma unroll
        for (int r = 0; r < 4; ++r)
            cc[mf][r] = c0[(size_t)(rowbase + mf * 16 + kb * 4 + r) * Hq + jbase + jh];

    floatx4 acc[2][2];
    half8 bf[8][2];                      // ring: 8 slots x 2 frags = 64 VGPRs

    for (int t = -1; t <= 255; ++t) {
        const int active = isL1 ? (t >= 0) : (t < 255);
        if (active) {
#pragma unroll
            for (int mf = 0; mf < 2; ++mf)
#pragma unroll
                for (int n = 0; n < 2; ++n)
                    acc[mf][n] = (floatx4){0.f, 0.f, 0.f, 0.f};

            const _Float16* bp = wlds + kb * 256 + jj * 8;

            if (isL1) {
                // gates1(t) = h_a(t)@Wih1^T + h_b(t-1)@Whh1^T  (64 K-steps)
                const _Float16* apA = bufA + (size_t)(t & 1) * BH
                                    + (size_t)(rowbase + jj) * Hq + kb * 8;
                const _Float16* apB = bufB + (size_t)((t + 1) & 1) * BH
                                    + (size_t)(rowbase + jj) * Hq + kb * 8;
#define L1P0(S) (((S) < 32) ? (apA + (S) * 32) : (apB + ((S) - 32) * 32))
#define L1P1(S) (L1P0(S) + 16 * Hq)
#pragma unroll
                for (int i = 0; i < 8; ++i) PISSUE(i, L1P0(i), L1P1(i));
#pragma unroll
                for (int s = 0; s < 56; ++s)
                    PSTEP14(s & 7, L1P0(s + 8), L1P1(s + 8));
                PSTEPW(0, 14); PSTEPW(1, 12); PSTEPW(2, 10); PSTEPW(3, 8);
                PSTEPW(4, 6);  PSTEPW(5, 4);  PSTEPW(6, 2);  PSTEPW(7, 0);
#undef L1P0
#undef L1P1
            } else {
                // gates0(t+1) = x(t+1)@Wih0^T + h_a(t)@Whh0^T  (36 K-steps)
                const _Float16* apX = xh + (size_t)(t + 1) * (Bq * 128)
                                    + (size_t)(rowbase + jj) * 128 + kb * 8;
                const _Float16* apA = bufA + (size_t)(t & 1) * BH
                                    + (size_t)(rowbase + jj) * Hq + kb * 8;
#define L0P0(S) (((S) < 4) ? (apX + (S) * 32) : (apA + ((S) - 4) * 32))
#define L0P1(S) (((S) < 4) ? (L0P0(S) + 16 * 128) : (L0P0(S) + 16 * Hq))
#pragma unroll
                for (int i = 0; i < 8; ++i) PISSUE(i, L0P0(i), L0P1(i));
#pragma unroll
                for (int s = 0; s < 28; ++s)
                    PSTEP14(s & 7, L0P0(s + 8), L0P1(s + 8));
                PSTEPW(4, 14); PSTEPW(5, 12); PSTEPW(6, 10); PSTEPW(7, 8);
                PSTEPW(0, 6);  PSTEPW(1, 4);  PSTEPW(2, 2);  PSTEPW(3, 0);
#undef L0P0
#undef L0P1
            }

            // ---- elementwise: gate-pair exchange + cell update + h store ----
            _Float16* hb = isL1 ? (bufB + (size_t)(t & 1) * BH)
                                : (bufA + (size_t)((t + 1) & 1) * BH);
            unsigned* hb32 = (unsigned*)hb;
#pragma unroll
            for (int mf = 0; mf < 2; ++mf) {
#pragma unroll
                for (int r = 0; r < 4; ++r) {
                    float o0 = acc[mf][0][r];       // lo: i, hi: f
                    float o1 = acc[mf][1][r];       // lo: g, hi: o
                    float p0 = __shfl_xor(o0, 8);
                    float p1 = __shfl_xor(o1, 8);
                    float gi = (lo ? o0 : p0) + bias[0];
                    float gf = (lo ? p0 : o0) + bias[1];
                    float gg = (lo ? o1 : p1) + bias[2];
                    float go = (lo ? p1 : o1) + bias[3];
                    float ii = 1.f / (1.f + expf(-gi));
                    float ff = 1.f / (1.f + expf(-gf));
                    float gt = tanhf(gg);
                    float oo = 1.f / (1.f + expf(-go));
                    float cn = ff * cc[mf][r] + ii * gt;
                    cc[mf][r] = cn;
                    float hn = oo * tanhf(cn);

                    union { _Float16 f; unsigned short u; } cv;
                    cv.f = (_Float16)hn;
                    int prt = __shfl_xor((int)cv.u, 1);   // neighbor j^1's bits
                    int row = rowbase + mf * 16 + kb * 4 + r;
                    if (lo && ((jh & 1) == 0)) {
                        unsigned word = (unsigned)cv.u | ((unsigned)prt << 16);
                        __hip_atomic_store(hb32 + (((size_t)row * Hq + jbase + jh) >> 1),
                                           word, __ATOMIC_RELAXED,
                                           __HIP_MEMORY_SCOPE_AGENT);
                    }
                    if (lo && isL1 && t == 255)
                        __hip_atomic_store(hbF + (size_t)row * Hq + jbase + jh,
                                           hn, __ATOMIC_RELAXED,
                                           __HIP_MEMORY_SCOPE_AGENT);
                }
            }
        }

        gridbar(sync, bid, (unsigned)(t + 2));
    }

    // ---- final: out[b][o] = b_out[o] + sum_k hbF[b][k] * Wout[o][k] ----
    int gid = bid * 512 + tid;
    if (gid < Bq * 128) {
        int b = gid >> 7, o = gid & 127;
        const floatx4* hr = (const floatx4*)(hbF + (size_t)b * Hq);
        const floatx4* wr = (const floatx4*)(Wout + (size_t)o * Hq);
        float s = bout[o];
#pragma unroll 4
        for (int k = 0; k < Hq / 4; ++k) {
            floatx4 hv = hr[k], wv = wr[k];
            s += hv[0] * wv[0] + hv[1] * wv[1] + hv[2] * wv[2] + hv[3] * wv[3];
        }
        out[gid] = s;
    }
}

// ---------------------------------------------------------------------------
extern "C" void kernel_launch(void* const* d_in, const int* in_sizes, int n_in,
                              void* d_out, int out_size, void* d_ws, size_t ws_size,
                              hipStream_t stream)
{
    (void)in_sizes; (void)n_in;
    float* out = (float*)d_out;

    if (ws_size < (size_t)REQ_WS) {
        float v = -(float)(ws_size >> 20);
        hipLaunchKernelGGL(ws_sentinel_kernel, dim3((out_size + 255) / 256), dim3(256),
                           0, stream, out, out_size, v);
        return;
    }

    const float* x    = (const float*)d_in[0];
    const float* h0   = (const float*)d_in[1];
    const float* c0   = (const float*)d_in[2];
    const float* Wih0 = (const float*)d_in[3];
    const float* Whh0 = (const float*)d_in[4];
    const float* bih0 = (const float*)d_in[5];
    const float* bhh0 = (const float*)d_in[6];
    const float* Wih1 = (const float*)d_in[7];
    const float* Whh1 = (const float*)d_in[8];
    const float* bih1 = (const float*)d_in[9];
    const float* bhh1 = (const float*)d_in[10];
    const float* Wout = (const float*)d_in[11];
    const float* bout = (const float*)d_in[12];

    char* ws = (char*)d_ws;
    _Float16* w1p  = (_Float16*)(ws + OFF_W1);
    _Float16* w0p  = (_Float16*)(ws + OFF_W0);
    _Float16* xh   = (_Float16*)(ws + OFF_XH);
    _Float16* bufA = (_Float16*)(ws + OFF_BA);
    _Float16* bufB = (_Float16*)(ws + OFF_BB);
    float*    hbF  = (float*)   (ws + OFF_HF);
    unsigned* sync = (unsigned*)(ws + OFF_SY);

    long long total = N_W1 + N_W0 + N_XH + N_H;   // 21,757,952 = 84992*256
    hipLaunchKernelGGL(prep_kernel, dim3((unsigned)(total / 256)), dim3(256), 0, stream,
                       x, h0, Wih0, Whh0, Wih1, Whh1, w1p, w0p, xh, bufA, bufB, sync);

    hipLaunchKernelGGL(lstm_main, dim3(256), dim3(512), 0, stream,
                       w1p, w0p, xh, bufA, bufB, hbF, c0,
                       bih0, bhh0, bih1, bhh1, Wout, bout, out, sync);
}

// Round 14
// 9624.971 us; speedup vs baseline: 1.0354x; 1.0051x over previous
//
#include <hip/hip_runtime.h>
#include <hip/hip_fp16.h>

// ---------------------------------------------------------------------------
// 2-layer LSTM (B=256, T=256, D=128, H=1024) + final Linear(H->128).
// Persistent kernel, one phase per timestep, flag-array grid barrier +
// per-phase per-CU acquire fence (R9 data plane). K-loop = R13's inline-asm
// ring-8 pipeline (16 loads in flight/wave, counted vmcnt).
//
// R14: BUSY-SPIN (DVFS probe). The spin loop replaces s_sleep with a
// 64-deep dependent FMA chain between polls, keeping SIMDs ~50% busy
// during barrier waits. Hypothesis: the invariant ~38us/phase across all
// structural variants is a LOW-CLOCK regime (DVFS settles at min clock for
// a ~15%-duty-cycle kernel); keeping the chip busy pins the clock high and
// contracts everything multiplicatively.
// ---------------------------------------------------------------------------

#define Bq 256
#define Hq 1024

typedef _Float16 half8 __attribute__((ext_vector_type(8)));
typedef float    floatx4 __attribute__((ext_vector_type(4)));

#define N_W1 8388608LL   // 128 cb * 65536  ([ks64][kb4][n2][jj16][e8])
#define N_W0 4718592LL   // 128 cb * 36864  ([ks36][kb4][n2][jj16][e8])
#define N_XH 8388608LL   // T*B*D
#define N_H  262144LL    // B*H
#define BH   262144

// ws byte offsets
#define OFF_W1 0LL
#define OFF_W0 16777216LL
#define OFF_XH 26214400LL
#define OFF_BA 42991616LL
#define OFF_BB 44040192LL
#define OFF_HF 45088768LL
#define OFF_SY 46137344LL
#define REQ_WS 46139392LL   // OFF_SY + 2048

// ---------------------------------------------------------------------------
__global__ void ws_sentinel_kernel(float* __restrict__ out, int n, float v)
{
    int i = blockIdx.x * blockDim.x + threadIdx.x;
    if (i < n) out[i] = v;
}

// ---------------------------------------------------------------------------
__global__ void prep_kernel(const float* __restrict__ x, const float* __restrict__ h0,
                            const float* __restrict__ Wih0, const float* __restrict__ Whh0,
                            const float* __restrict__ Wih1, const float* __restrict__ Whh1,
                            _Float16* __restrict__ w1p, _Float16* __restrict__ w0p,
                            _Float16* __restrict__ xh,
                            _Float16* __restrict__ bufA, _Float16* __restrict__ bufB,
                            unsigned* __restrict__ sync)
{
    long long gid = (long long)blockIdx.x * blockDim.x + threadIdx.x;
    if (gid < 512) sync[gid] = 0u;   // 256 arrival flags (monotonic) + spare

    if (gid < N_W1) {
        // [cb][ks][kb][n][jj][e]; gate-col row = (2n + jj>>3)*1024 + cb*8 + (jj&7)
        long long i = gid;
        int e  = (int)(i & 7);
        int jj = (int)((i >> 3) & 15);
        int n  = (int)((i >> 7) & 1);
        int kb = (int)((i >> 8) & 3);
        int ks = (int)((i >> 10) & 63);
        int cb = (int)(i >> 16);
        int row = (2 * n + (jj >> 3)) * 1024 + cb * 8 + (jj & 7);
        int k = ks * 32 + kb * 8 + e;
        float v = (k < 1024) ? Wih1[(size_t)row * 1024 + k]
                             : Whh1[(size_t)row * 1024 + (k - 1024)];
        w1p[i] = (_Float16)v;
    } else if (gid < N_W1 + N_W0) {
        long long i = gid - N_W1;
        int cb = (int)(i / 36864LL);
        int r  = (int)(i - (long long)cb * 36864LL);
        int ks = r >> 10;
        int kb = (r >> 8) & 3;
        int n  = (r >> 7) & 1;
        int jj = (r >> 3) & 15;
        int e  = r & 7;
        int row = (2 * n + (jj >> 3)) * 1024 + cb * 8 + (jj & 7);
        int k = ks * 32 + kb * 8 + e;
        float v = (k < 128) ? Wih0[(size_t)row * 128 + k]
                            : Whh0[(size_t)row * 1024 + (k - 128)];
        w0p[i] = (_Float16)v;
    } else if (gid < N_W1 + N_W0 + N_XH) {
        long long i = gid - N_W1 - N_W0;
        // xh[t][b][d] = x[b][t][d]
        int d = (int)(i & 127);
        int b = (int)((i >> 7) & 255);
        int t = (int)(i >> 15);
        xh[i] = (_Float16)x[((size_t)b * 256 + t) * 128 + d];
    } else if (gid < N_W1 + N_W0 + N_XH + N_H) {
        long long i = gid - N_W1 - N_W0 - N_XH;
        _Float16 v = (_Float16)h0[i];
        bufA[BH + i] = v;   // h_a(-1) parity 1
        bufB[BH + i] = v;   // h_b(-1) parity 1
    }
}

// ---------------------------------------------------------------------------
// Parallel flag-array grid barrier with BUSY spin (no s_sleep): each poll
// iteration runs a 64-deep dependent FMA chain to keep the SIMDs active
// (DVFS probe). Semantics identical to R9/R13's barrier.
__device__ __forceinline__ void gridbar(unsigned* flags, int bid, unsigned target)
{
    __builtin_amdgcn_s_waitcnt(0);     // own write-through stores drained
    __syncthreads();
    if (threadIdx.x == 0)
        __hip_atomic_store(flags + bid, target, __ATOMIC_RELAXED,
                           __HIP_MEMORY_SCOPE_AGENT);
    if (threadIdx.x < 256) {
        float z = 1.0f + (float)(threadIdx.x & 7);
        int guard = 0;
        while (__hip_atomic_load(flags + threadIdx.x, __ATOMIC_RELAXED,
                                 __HIP_MEMORY_SCOPE_AGENT) < target) {
#pragma unroll
            for (int i = 0; i < 64; ++i)
                z = __builtin_fmaf(z, 1.0000002f, 1.0e-7f);
            asm volatile("" :: "v"(z));            // keep the chain live
            if (++guard > (1 << 15)) break;        // safety: wrong, not wedged
        }
    }
    __syncthreads();
    if (threadIdx.x < 64)                           // one inv per CU (L1+L2)
        __builtin_amdgcn_fence(__ATOMIC_ACQUIRE, "agent");
    __syncthreads();
}

#define MFMA16(A, Bv, C) __builtin_amdgcn_mfma_f32_16x16x32_f16((A), (Bv), (C), 0, 0, 0)

// ---- inline-asm pipelined K-step machinery (R13, unchanged) ---------------
#define PISSUE(I, P0, P1)                                           \
    asm volatile("global_load_dwordx4 %0, %2, off\n\t"              \
                 "global_load_dwordx4 %1, %3, off"                  \
                 : "=&v"(bf[I][0]), "=&v"(bf[I][1])                 \
                 : "v"(P0), "v"(P1) : "memory")

#define PSTEP14(I, P0, P1) do {                                     \
    half8 b0 = *(const half8*)(bp);                                 \
    half8 b1 = *(const half8*)(bp + 128);                           \
    asm volatile("s_waitcnt vmcnt(14)" ::: "memory");               \
    __builtin_amdgcn_sched_barrier(0);                              \
    acc[0][0] = MFMA16(bf[I][0], b0, acc[0][0]);                    \
    acc[0][1] = MFMA16(bf[I][0], b1, acc[0][1]);                    \
    acc[1][0] = MFMA16(bf[I][1], b0, acc[1][0]);                    \
    acc[1][1] = MFMA16(bf[I][1], b1, acc[1][1]);                    \
    bp += 1024;                                                     \
    PISSUE(I, P0, P1);                                              \
} while (0)

#define PSTEPW(I, NLIT) do {                                        \
    half8 b0 = *(const half8*)(bp);                                 \
    half8 b1 = *(const half8*)(bp + 128);                           \
    asm volatile("s_waitcnt vmcnt(" #NLIT ")" ::: "memory");        \
    __builtin_amdgcn_sched_barrier(0);                              \
    acc[0][0] = MFMA16(bf[I][0], b0, acc[0][0]);                    \
    acc[0][1] = MFMA16(bf[I][0], b1, acc[0][1]);                    \
    acc[1][0] = MFMA16(bf[I][1], b0, acc[1][0]);                    \
    acc[1][1] = MFMA16(bf[I][1], b1, acc[1][1]);                    \
    bp += 1024;                                                     \
} while (0)

__global__ void __launch_bounds__(512)
lstm_main(const _Float16* __restrict__ w1p, const _Float16* __restrict__ w0p,
          const _Float16* __restrict__ xh,
          _Float16* __restrict__ bufA, _Float16* __restrict__ bufB,
          float* __restrict__ hbF,
          const float* __restrict__ c0,
          const float* __restrict__ bih0, const float* __restrict__ bhh0,
          const float* __restrict__ bih1, const float* __restrict__ bhh1,
          const float* __restrict__ Wout, const float* __restrict__ bout,
          float* __restrict__ out, unsigned* __restrict__ sync)
{
    __shared__ _Float16 wlds[65536];   // 128 KiB

    const int tid  = threadIdx.x;
    const int lane = tid & 63;
    const int w    = tid >> 6;           // 0..7
    const int bid  = blockIdx.x;
    const int xcd  = bid & 7;
    const int slot = bid >> 3;           // 0..31
    const int isL1 = ((slot & 1) == 0);  // 16 L1 + 16 L0 blocks per XCD
    const int cb   = xcd * 16 + (slot >> 1);   // 0..127 column-block id
    const int jbase = cb * 8;
    const int jj = lane & 15;
    const int kb = lane >> 4;            // 0..3
    const int jh = jj & 7;
    const int lo = (jj < 8);
    const int rowbase = w * 32;          // wave's 32 batch rows

    // ---- load this block's weights into LDS (once) ----
    {
        const _Float16* src = isL1 ? (w1p + (size_t)cb * 65536)
                                   : (w0p + (size_t)cb * 36864);
        const int nch = isL1 ? 8192 : 4608;   // 16B chunks
        for (int i = tid; i < nch; i += 512)
            *(half8*)&wlds[(size_t)i * 8] = *(const half8*)&src[(size_t)i * 8];
    }
    __syncthreads();

    // ---- biases + cell-state init ----
    const float* bi  = isL1 ? bih1 : bih0;
    const float* bhp = isL1 ? bhh1 : bhh0;
    float bias[4];
#pragma unroll
    for (int g = 0; g < 4; ++g)
        bias[g] = bi[g * 1024 + jbase + jh] + bhp[g * 1024 + jbase + jh];

    float cc[2][4];
#pragma unroll
    for (int mf = 0; mf < 2; ++mf)
#pragma unroll
        for (int r = 0; r < 4; ++r)
            cc[mf][r] = c0[(size_t)(rowbase + mf * 16 + kb * 4 + r) * Hq + jbase + jh];

    floatx4 acc[2][2];
    half8 bf[8][2];                      // ring: 8 slots x 2 frags = 64 VGPRs

    for (int t = -1; t <= 255; ++t) {
        const int active = isL1 ? (t >= 0) : (t < 255);
        if (active) {
#pragma unroll
            for (int mf = 0; mf < 2; ++mf)
#pragma unroll
                for (int n = 0; n < 2; ++n)
                    acc[mf][n] = (floatx4){0.f, 0.f, 0.f, 0.f};

            const _Float16* bp = wlds + kb * 256 + jj * 8;

            if (isL1) {
                // gates1(t) = h_a(t)@Wih1^T + h_b(t-1)@Whh1^T  (64 K-steps)
                const _Float16* apA = bufA + (size_t)(t & 1) * BH
                                    + (size_t)(rowbase + jj) * Hq + kb * 8;
                const _Float16* apB = bufB + (size_t)((t + 1) & 1) * BH
                                    + (size_t)(rowbase + jj) * Hq + kb * 8;
#define L1P0(S) (((S) < 32) ? (apA + (S) * 32) : (apB + ((S) - 32) * 32))
#define L1P1(S) (L1P0(S) + 16 * Hq)
#pragma unroll
                for (int i = 0; i < 8; ++i) PISSUE(i, L1P0(i), L1P1(i));
#pragma unroll
                for (int s = 0; s < 56; ++s)
                    PSTEP14(s & 7, L1P0(s + 8), L1P1(s + 8));
                PSTEPW(0, 14); PSTEPW(1, 12); PSTEPW(2, 10); PSTEPW(3, 8);
                PSTEPW(4, 6);  PSTEPW(5, 4);  PSTEPW(6, 2);  PSTEPW(7, 0);
#undef L1P0
#undef L1P1
            } else {
                // gates0(t+1) = x(t+1)@Wih0^T + h_a(t)@Whh0^T  (36 K-steps)
                const _Float16* apX = xh + (size_t)(t + 1) * (Bq * 128)
                                    + (size_t)(rowbase + jj) * 128 + kb * 8;
                const _Float16* apA = bufA + (size_t)(t & 1) * BH
                                    + (size_t)(rowbase + jj) * Hq + kb * 8;
#define L0P0(S) (((S) < 4) ? (apX + (S) * 32) : (apA + ((S) - 4) * 32))
#define L0P1(S) (((S) < 4) ? (L0P0(S) + 16 * 128) : (L0P0(S) + 16 * Hq))
#pragma unroll
                for (int i = 0; i < 8; ++i) PISSUE(i, L0P0(i), L0P1(i));
#pragma unroll
                for (int s = 0; s < 28; ++s)
                    PSTEP14(s & 7, L0P0(s + 8), L0P1(s + 8));
                PSTEPW(4, 14); PSTEPW(5, 12); PSTEPW(6, 10); PSTEPW(7, 8);
                PSTEPW(0, 6);  PSTEPW(1, 4);  PSTEPW(2, 2);  PSTEPW(3, 0);
#undef L0P0
#undef L0P1
            }

            // ---- elementwise: gate-pair exchange + cell update + h store ----
            _Float16* hb = isL1 ? (bufB + (size_t)(t & 1) * BH)
                                : (bufA + (size_t)((t + 1) & 1) * BH);
            unsigned* hb32 = (unsigned*)hb;
#pragma unroll
            for (int mf = 0; mf < 2; ++mf) {
#pragma unroll
                for (int r = 0; r < 4; ++r) {
                    float o0 = acc[mf][0][r];       // lo: i, hi: f
                    float o1 = acc[mf][1][r];       // lo: g, hi: o
                    float p0 = __shfl_xor(o0, 8);
                    float p1 = __shfl_xor(o1, 8);
                    float gi = (lo ? o0 : p0) + bias[0];
                    float gf = (lo ? p0 : o0) + bias[1];
                    float gg = (lo ? o1 : p1) + bias[2];
                    float go = (lo ? p1 : o1) + bias[3];
                    float ii = 1.f / (1.f + expf(-gi));
                    float ff = 1.f / (1.f + expf(-gf));
                    float gt = tanhf(gg);
                    float oo = 1.f / (1.f + expf(-go));
                    float cn = ff * cc[mf][r] + ii * gt;
                    cc[mf][r] = cn;
                    float hn = oo * tanhf(cn);

                    union { _Float16 f; unsigned short u; } cv;
                    cv.f = (_Float16)hn;
                    int prt = __shfl_xor((int)cv.u, 1);   // neighbor j^1's bits
                    int row = rowbase + mf * 16 + kb * 4 + r;
                    if (lo && ((jh & 1) == 0)) {
                        unsigned word = (unsigned)cv.u | ((unsigned)prt << 16);
                        __hip_atomic_store(hb32 + (((size_t)row * Hq + jbase + jh) >> 1),
                                           word, __ATOMIC_RELAXED,
                                           __HIP_MEMORY_SCOPE_AGENT);
                    }
                    if (lo && isL1 && t == 255)
                        __hip_atomic_store(hbF + (size_t)row * Hq + jbase + jh,
                                           hn, __ATOMIC_RELAXED,
                                           __HIP_MEMORY_SCOPE_AGENT);
                }
            }
        }

        gridbar(sync, bid, (unsigned)(t + 2));
    }

    // ---- final: out[b][o] = b_out[o] + sum_k hbF[b][k] * Wout[o][k] ----
    int gid = bid * 512 + tid;
    if (gid < Bq * 128) {
        int b = gid >> 7, o = gid & 127;
        const floatx4* hr = (const floatx4*)(hbF + (size_t)b * Hq);
        const floatx4* wr = (const floatx4*)(Wout + (size_t)o * Hq);
        float s = bout[o];
#pragma unroll 4
        for (int k = 0; k < Hq / 4; ++k) {
            floatx4 hv = hr[k], wv = wr[k];
            s += hv[0] * wv[0] + hv[1] * wv[1] + hv[2] * wv[2] + hv[3] * wv[3];
        }
        out[gid] = s;
    }
}

// ---------------------------------------------------------------------------
extern "C" void kernel_launch(void* const* d_in, const int* in_sizes, int n_in,
                              void* d_out, int out_size, void* d_ws, size_t ws_size,
                              hipStream_t stream)
{
    (void)in_sizes; (void)n_in;
    float* out = (float*)d_out;

    if (ws_size < (size_t)REQ_WS) {
        float v = -(float)(ws_size >> 20);
        hipLaunchKernelGGL(ws_sentinel_kernel, dim3((out_size + 255) / 256), dim3(256),
                           0, stream, out, out_size, v);
        return;
    }

    const float* x    = (const float*)d_in[0];
    const float* h0   = (const float*)d_in[1];
    const float* c0   = (const float*)d_in[2];
    const float* Wih0 = (const float*)d_in[3];
    const float* Whh0 = (const float*)d_in[4];
    const float* bih0 = (const float*)d_in[5];
    const float* bhh0 = (const float*)d_in[6];
    const float* Wih1 = (const float*)d_in[7];
    const float* Whh1 = (const float*)d_in[8];
    const float* bih1 = (const float*)d_in[9];
    const float* bhh1 = (const float*)d_in[10];
    const float* Wout = (const float*)d_in[11];
    const float* bout = (const float*)d_in[12];

    char* ws = (char*)d_ws;
    _Float16* w1p  = (_Float16*)(ws + OFF_W1);
    _Float16* w0p  = (_Float16*)(ws + OFF_W0);
    _Float16* xh   = (_Float16*)(ws + OFF_XH);
    _Float16* bufA = (_Float16*)(ws + OFF_BA);
    _Float16* bufB = (_Float16*)(ws + OFF_BB);
    float*    hbF  = (float*)   (ws + OFF_HF);
    unsigned* sync = (unsigned*)(ws + OFF_SY);

    long long total = N_W1 + N_W0 + N_XH + N_H;   // 21,757,952 = 84992*256
    hipLaunchKernelGGL(prep_kernel, dim3((unsigned)(total / 256)), dim3(256), 0, stream,
                       x, h0, Wih0, Whh0, Wih1, Whh1, w1p, w0p, xh, bufA, bufB, sync);

    hipLaunchKernelGGL(lstm_main, dim3(256), dim3(512), 0, stream,
                       w1p, w0p, xh, bufA, bufB, hbF, c0,
                       bih0, bhh0, bih1, bhh1, Wout, bout, out, sync);
}

// Round 18
// 9360.920 us; speedup vs baseline: 1.0646x; 1.0282x over previous
//
#include <hip/hip_runtime.h>
#include <hip/hip_fp16.h>

// ---------------------------------------------------------------------------
// 2-layer LSTM (B=256, T=256, D=128, H=1024) + final Linear(H->128).
// Persistent kernel, one phase per timestep, flag-array grid barrier.
// K-loop = R13's inline-asm ring-8 pipeline. fp16 MFMA, fp32 accum.
//
// R15 (resubmit R18): SINGLE L2-INVALIDATE PER XCD PER PHASE. Hypothesis:
// the invariant ~38us/phase is 32 redundant agent-acquire fences
// (buffer_inv sc1 = full XCD-L2 invalidate) serializing at each XCD's L2
// every phase. New protocol:
//   gridbar (fence-free) -> slot-0 block per XCD: agent fence (L2+L1 inv),
//   vmcnt(0), publish xcdgo[xcd] -> other 31 blocks poll xcdgo, then plain
//   buffer_inv (L1-only) -> cached compute.
// The t=255 round also freshens hbF for the final GEMM.
// ---------------------------------------------------------------------------

#define Bq 256
#define Hq 1024

typedef _Float16 half8 __attribute__((ext_vector_type(8)));
typedef float    floatx4 __attribute__((ext_vector_type(4)));

#define N_W1 8388608LL   // 128 cb * 65536  ([ks64][kb4][n2][jj16][e8])
#define N_W0 4718592LL   // 128 cb * 36864  ([ks36][kb4][n2][jj16][e8])
#define N_XH 8388608LL   // T*B*D
#define N_H  262144LL    // B*H
#define BH   262144

// ws byte offsets
#define OFF_W1 0LL
#define OFF_W0 16777216LL
#define OFF_XH 26214400LL
#define OFF_BA 42991616LL
#define OFF_BB 44040192LL
#define OFF_HF 45088768LL
#define OFF_SY 46137344LL
#define REQ_WS 46139392LL   // OFF_SY + 2048

// ---------------------------------------------------------------------------
__global__ void ws_sentinel_kernel(float* __restrict__ out, int n, float v)
{
    int i = blockIdx.x * blockDim.x + threadIdx.x;
    if (i < n) out[i] = v;
}

// ---------------------------------------------------------------------------
__global__ void prep_kernel(const float* __restrict__ x, const float* __restrict__ h0,
                            const float* __restrict__ Wih0, const float* __restrict__ Whh0,
                            const float* __restrict__ Wih1, const float* __restrict__ Whh1,
                            _Float16* __restrict__ w1p, _Float16* __restrict__ w0p,
                            _Float16* __restrict__ xh,
                            _Float16* __restrict__ bufA, _Float16* __restrict__ bufB,
                            unsigned* __restrict__ sync)
{
    long long gid = (long long)blockIdx.x * blockDim.x + threadIdx.x;
    if (gid < 512) sync[gid] = 0u;   // [0..255] global flags, [256..511] xcdgo

    if (gid < N_W1) {
        // [cb][ks][kb][n][jj][e]; gate-col row = (2n + jj>>3)*1024 + cb*8 + (jj&7)
        long long i = gid;
        int e  = (int)(i & 7);
        int jj = (int)((i >> 3) & 15);
        int n  = (int)((i >> 7) & 1);
        int kb = (int)((i >> 8) & 3);
        int ks = (int)((i >> 10) & 63);
        int cb = (int)(i >> 16);
        int row = (2 * n + (jj >> 3)) * 1024 + cb * 8 + (jj & 7);
        int k = ks * 32 + kb * 8 + e;
        float v = (k < 1024) ? Wih1[(size_t)row * 1024 + k]
                             : Whh1[(size_t)row * 1024 + (k - 1024)];
        w1p[i] = (_Float16)v;
    } else if (gid < N_W1 + N_W0) {
        long long i = gid - N_W1;
        int cb = (int)(i / 36864LL);
        int r  = (int)(i - (long long)cb * 36864LL);
        int ks = r >> 10;
        int kb = (r >> 8) & 3;
        int n  = (r >> 7) & 1;
        int jj = (r >> 3) & 15;
        int e  = r & 7;
        int row = (2 * n + (jj >> 3)) * 1024 + cb * 8 + (jj & 7);
        int k = ks * 32 + kb * 8 + e;
        float v = (k < 128) ? Wih0[(size_t)row * 128 + k]
                            : Whh0[(size_t)row * 1024 + (k - 128)];
        w0p[i] = (_Float16)v;
    } else if (gid < N_W1 + N_W0 + N_XH) {
        long long i = gid - N_W1 - N_W0;
        // xh[t][b][d] = x[b][t][d]
        int d = (int)(i & 127);
        int b = (int)((i >> 7) & 255);
        int t = (int)(i >> 15);
        xh[i] = (_Float16)x[((size_t)b * 256 + t) * 128 + d];
    } else if (gid < N_W1 + N_W0 + N_XH + N_H) {
        long long i = gid - N_W1 - N_W0 - N_XH;
        _Float16 v = (_Float16)h0[i];
        bufA[BH + i] = v;   // h_a(-1) parity 1
        bufB[BH + i] = v;   // h_b(-1) parity 1
    }
}

// ---------------------------------------------------------------------------
// Global flag-array barrier, fence-free (freshness handled by invround).
__device__ __forceinline__ void gridbar(unsigned* flags, int bid, unsigned target)
{
    __builtin_amdgcn_s_waitcnt(0);     // own write-through stores at IF
    __syncthreads();
    if (threadIdx.x == 0)
        __hip_atomic_store(flags + bid, target, __ATOMIC_RELAXED,
                           __HIP_MEMORY_SCOPE_AGENT);
    if (threadIdx.x < 256) {
        int guard = 0;
        while (__hip_atomic_load(flags + threadIdx.x, __ATOMIC_RELAXED,
                                 __HIP_MEMORY_SCOPE_AGENT) < target) {
            __builtin_amdgcn_s_sleep(1);
            if (++guard > (1 << 18)) break;        // safety: wrong, not wedged
        }
    }
    __syncthreads();
}

// ---------------------------------------------------------------------------
// Per-XCD single-L2-invalidate round. slot-0 block: agent acquire fence
// (L2+L1 inv) + completion wait + publish. Others: poll, then L1-only inv.
__device__ __forceinline__ void invround(unsigned* xcdgo, int slot, unsigned target)
{
    if (slot == 0) {
        if (threadIdx.x < 64) {
            __builtin_amdgcn_fence(__ATOMIC_ACQUIRE, "agent");   // buffer_inv sc1
            asm volatile("s_waitcnt vmcnt(0) lgkmcnt(0)" ::: "memory");
            if (threadIdx.x == 0)
                __hip_atomic_store(xcdgo, target, __ATOMIC_RELAXED,
                                   __HIP_MEMORY_SCOPE_AGENT);
        }
        __syncthreads();      // whole block (same CU) now fresh
    } else {
        if (threadIdx.x == 0) {
            int guard = 0;
            while (__hip_atomic_load(xcdgo, __ATOMIC_RELAXED,
                                     __HIP_MEMORY_SCOPE_AGENT) < target) {
                __builtin_amdgcn_s_sleep(1);
                if (++guard > (1 << 18)) break;
            }
        }
        __syncthreads();      // all waves gated until L2 is clean
        if (threadIdx.x == 0) {
            asm volatile("buffer_inv" ::: "memory");             // L1-only
            asm volatile("s_waitcnt vmcnt(0)" ::: "memory");
        }
        __syncthreads();
    }
}

#define MFMA16(A, Bv, C) __builtin_amdgcn_mfma_f32_16x16x32_f16((A), (Bv), (C), 0, 0, 0)

// ---- inline-asm pipelined K-step machinery (R13, unchanged) ---------------
#define PISSUE(I, P0, P1)                                           \
    asm volatile("global_load_dwordx4 %0, %2, off\n\t"              \
                 "global_load_dwordx4 %1, %3, off"                  \
                 : "=&v"(bf[I][0]), "=&v"(bf[I][1])                 \
                 : "v"(P0), "v"(P1) : "memory")

#define PSTEP14(I, P0, P1) do {                                     \
    half8 b0 = *(const half8*)(bp);                                 \
    half8 b1 = *(const half8*)(bp + 128);                           \
    asm volatile("s_waitcnt vmcnt(14)" ::: "memory");               \
    __builtin_amdgcn_sched_barrier(0);                              \
    acc[0][0] = MFMA16(bf[I][0], b0, acc[0][0]);                    \
    acc[0][1] = MFMA16(bf[I][0], b1, acc[0][1]);                    \
    acc[1][0] = MFMA16(bf[I][1], b0, acc[1][0]);                    \
    acc[1][1] = MFMA16(bf[I][1], b1, acc[1][1]);                    \
    bp += 1024;                                                     \
    PISSUE(I, P0, P1);                                              \
} while (0)

#define PSTEPW(I, NLIT) do {                                        \
    half8 b0 = *(const half8*)(bp);                                 \
    half8 b1 = *(const half8*)(bp + 128);                           \
    asm volatile("s_waitcnt vmcnt(" #NLIT ")" ::: "memory");        \
    __builtin_amdgcn_sched_barrier(0);                              \
    acc[0][0] = MFMA16(bf[I][0], b0, acc[0][0]);                    \
    acc[0][1] = MFMA16(bf[I][0], b1, acc[0][1]);                    \
    acc[1][0] = MFMA16(bf[I][1], b0, acc[1][0]);                    \
    acc[1][1] = MFMA16(bf[I][1], b1, acc[1][1]);                    \
    bp += 1024;                                                     \
} while (0)

__global__ void __launch_bounds__(512)
lstm_main(const _Float16* __restrict__ w1p, const _Float16* __restrict__ w0p,
          const _Float16* __restrict__ xh,
          _Float16* __restrict__ bufA, _Float16* __restrict__ bufB,
          float* __restrict__ hbF,
          const float* __restrict__ c0,
          const float* __restrict__ bih0, const float* __restrict__ bhh0,
          const float* __restrict__ bih1, const float* __restrict__ bhh1,
          const float* __restrict__ Wout, const float* __restrict__ bout,
          float* __restrict__ out, unsigned* __restrict__ sync)
{
    __shared__ _Float16 wlds[65536];   // 128 KiB

    const int tid  = threadIdx.x;
    const int lane = tid & 63;
    const int w    = tid >> 6;           // 0..7
    const int bid  = blockIdx.x;
    const int xcd  = bid & 7;
    const int slot = bid >> 3;           // 0..31
    const int isL1 = ((slot & 1) == 0);  // 16 L1 + 16 L0 blocks per XCD
    const int cb   = xcd * 16 + (slot >> 1);   // 0..127 column-block id
    const int jbase = cb * 8;
    const int jj = lane & 15;
    const int kb = lane >> 4;            // 0..3
    const int jh = jj & 7;
    const int lo = (jj < 8);
    const int rowbase = w * 32;          // wave's 32 batch rows

    unsigned* xcdgo = sync + 256 + xcd * 16;   // 64B-separated per-XCD flags

    // ---- load this block's weights into LDS (once) ----
    {
        const _Float16* src = isL1 ? (w1p + (size_t)cb * 65536)
                                   : (w0p + (size_t)cb * 36864);
        const int nch = isL1 ? 8192 : 4608;   // 16B chunks
        for (int i = tid; i < nch; i += 512)
            *(half8*)&wlds[(size_t)i * 8] = *(const half8*)&src[(size_t)i * 8];
    }
    __syncthreads();

    // ---- biases + cell-state init ----
    const float* bi  = isL1 ? bih1 : bih0;
    const float* bhp = isL1 ? bhh1 : bhh0;
    float bias[4];
#pragma unroll
    for (int g = 0; g < 4; ++g)
        bias[g] = bi[g * 1024 + jbase + jh] + bhp[g * 1024 + jbase + jh];

    float cc[2][4];
#pragma unroll
    for (int mf = 0; mf < 2; ++mf)
#pragma unroll
        for (int r = 0; r < 4; ++r)
            cc[mf][r] = c0[(size_t)(rowbase + mf * 16 + kb * 4 + r) * Hq + jbase + jh];

    floatx4 acc[2][2];
    half8 bf[8][2];                      // ring: 8 slots x 2 frags = 64 VGPRs

    for (int t = -1; t <= 255; ++t) {
        const int active = isL1 ? (t >= 0) : (t < 255);
        if (active) {
#pragma unroll
            for (int mf = 0; mf < 2; ++mf)
#pragma unroll
                for (int n = 0; n < 2; ++n)
                    acc[mf][n] = (floatx4){0.f, 0.f, 0.f, 0.f};

            const _Float16* bp = wlds + kb * 256 + jj * 8;

            if (isL1) {
                // gates1(t) = h_a(t)@Wih1^T + h_b(t-1)@Whh1^T  (64 K-steps)
                const _Float16* apA = bufA + (size_t)(t & 1) * BH
                                    + (size_t)(rowbase + jj) * Hq + kb * 8;
                const _Float16* apB = bufB + (size_t)((t + 1) & 1) * BH
                                    + (size_t)(rowbase + jj) * Hq + kb * 8;
#define L1P0(S) (((S) < 32) ? (apA + (S) * 32) : (apB + ((S) - 32) * 32))
#define L1P1(S) (L1P0(S) + 16 * Hq)
#pragma unroll
                for (int i = 0; i < 8; ++i) PISSUE(i, L1P0(i), L1P1(i));
#pragma unroll
                for (int s = 0; s < 56; ++s)
                    PSTEP14(s & 7, L1P0(s + 8), L1P1(s + 8));
                PSTEPW(0, 14); PSTEPW(1, 12); PSTEPW(2, 10); PSTEPW(3, 8);
                PSTEPW(4, 6);  PSTEPW(5, 4);  PSTEPW(6, 2);  PSTEPW(7, 0);
#undef L1P0
#undef L1P1
            } else {
                // gates0(t+1) = x(t+1)@Wih0^T + h_a(t)@Whh0^T  (36 K-steps)
                const _Float16* apX = xh + (size_t)(t + 1) * (Bq * 128)
                                    + (size_t)(rowbase + jj) * 128 + kb * 8;
                const _Float16* apA = bufA + (size_t)(t & 1) * BH
                                    + (size_t)(rowbase + jj) * Hq + kb * 8;
#define L0P0(S) (((S) < 4) ? (apX + (S) * 32) : (apA + ((S) - 4) * 32))
#define L0P1(S) (((S) < 4) ? (L0P0(S) + 16 * 128) : (L0P0(S) + 16 * Hq))
#pragma unroll
                for (int i = 0; i < 8; ++i) PISSUE(i, L0P0(i), L0P1(i));
#pragma unroll
                for (int s = 0; s < 28; ++s)
                    PSTEP14(s & 7, L0P0(s + 8), L0P1(s + 8));
                PSTEPW(4, 14); PSTEPW(5, 12); PSTEPW(6, 10); PSTEPW(7, 8);
                PSTEPW(0, 6);  PSTEPW(1, 4);  PSTEPW(2, 2);  PSTEPW(3, 0);
#undef L0P0
#undef L0P1
            }

            // ---- elementwise: gate-pair exchange + cell update + h store ----
            _Float16* hb = isL1 ? (bufB + (size_t)(t & 1) * BH)
                                : (bufA + (size_t)((t + 1) & 1) * BH);
            unsigned* hb32 = (unsigned*)hb;
#pragma unroll
            for (int mf = 0; mf < 2; ++mf) {
#pragma unroll
                for (int r = 0; r < 4; ++r) {
                    float o0 = acc[mf][0][r];       // lo: i, hi: f
                    float o1 = acc[mf][1][r];       // lo: g, hi: o
                    float p0 = __shfl_xor(o0, 8);
                    float p1 = __shfl_xor(o1, 8);
                    float gi = (lo ? o0 : p0) + bias[0];
                    float gf = (lo ? p0 : o0) + bias[1];
                    float gg = (lo ? o1 : p1) + bias[2];
                    float go = (lo ? p1 : o1) + bias[3];
                    float ii = 1.f / (1.f + expf(-gi));
                    float ff = 1.f / (1.f + expf(-gf));
                    float gt = tanhf(gg);
                    float oo = 1.f / (1.f + expf(-go));
                    float cn = ff * cc[mf][r] + ii * gt;
                    cc[mf][r] = cn;
                    float hn = oo * tanhf(cn);

                    union { _Float16 f; unsigned short u; } cv;
                    cv.f = (_Float16)hn;
                    int prt = __shfl_xor((int)cv.u, 1);   // neighbor j^1's bits
                    int row = rowbase + mf * 16 + kb * 4 + r;
                    if (lo && ((jh & 1) == 0)) {
                        unsigned word = (unsigned)cv.u | ((unsigned)prt << 16);
                        __hip_atomic_store(hb32 + (((size_t)row * Hq + jbase + jh) >> 1),
                                           word, __ATOMIC_RELAXED,
                                           __HIP_MEMORY_SCOPE_AGENT);
                    }
                    if (lo && isL1 && t == 255)
                        __hip_atomic_store(hbF + (size_t)row * Hq + jbase + jh,
                                           hn, __ATOMIC_RELAXED,
                                           __HIP_MEMORY_SCOPE_AGENT);
                }
            }
        }

        gridbar(sync, bid, (unsigned)(t + 2));
        invround(xcdgo, slot, (unsigned)(t + 2));
    }

    // ---- final: out[b][o] = b_out[o] + sum_k hbF[b][k] * Wout[o][k] ----
    // (t=255 invround already freshened L2/L1 for hbF's cached reads)
    int gid = bid * 512 + tid;
    if (gid < Bq * 128) {
        int b = gid >> 7, o = gid & 127;
        const floatx4* hr = (const floatx4*)(hbF + (size_t)b * Hq);
        const floatx4* wr = (const floatx4*)(Wout + (size_t)o * Hq);
        float s = bout[o];
#pragma unroll 4
        for (int k = 0; k < Hq / 4; ++k) {
            floatx4 hv = hr[k], wv = wr[k];
            s += hv[0] * wv[0] + hv[1] * wv[1] + hv[2] * wv[2] + hv[3] * wv[3];
        }
        out[gid] = s;
    }
}

// ---------------------------------------------------------------------------
extern "C" void kernel_launch(void* const* d_in, const int* in_sizes, int n_in,
                              void* d_out, int out_size, void* d_ws, size_t ws_size,
                              hipStream_t stream)
{
    (void)in_sizes; (void)n_in;
    float* out = (float*)d_out;

    if (ws_size < (size_t)REQ_WS) {
        float v = -(float)(ws_size >> 20);
        hipLaunchKernelGGL(ws_sentinel_kernel, dim3((out_size + 255) / 256), dim3(256),
                           0, stream, out, out_size, v);
        return;
    }

    const float* x    = (const float*)d_in[0];
    const float* h0   = (const float*)d_in[1];
    const float* c0   = (const float*)d_in[2];
    const float* Wih0 = (const float*)d_in[3];
    const float* Whh0 = (const float*)d_in[4];
    const float* bih0 = (const float*)d_in[5];
    const float* bhh0 = (const float*)d_in[6];
    const float* Wih1 = (const float*)d_in[7];
    const float* Whh1 = (const float*)d_in[8];
    const float* bih1 = (const float*)d_in[9];
    const float* bhh1 = (const float*)d_in[10];
    const float* Wout = (const float*)d_in[11];
    const float* bout = (const float*)d_in[12];

    char* ws = (char*)d_ws;
    _Float16* w1p  = (_Float16*)(ws + OFF_W1);
    _Float16* w0p  = (_Float16*)(ws + OFF_W0);
    _Float16* xh   = (_Float16*)(ws + OFF_XH);
    _Float16* bufA = (_Float16*)(ws + OFF_BA);
    _Float16* bufB = (_Float16*)(ws + OFF_BB);
    float*    hbF  = (float*)   (ws + OFF_HF);
    unsigned* sync = (unsigned*)(ws + OFF_SY);

    long long total = N_W1 + N_W0 + N_XH + N_H;   // 21,757,952 = 84992*256
    hipLaunchKernelGGL(prep_kernel, dim3((unsigned)(total / 256)), dim3(256), 0, stream,
                       x, h0, Wih0, Whh0, Wih1, Whh1, w1p, w0p, xh, bufA, bufB, sync);

    hipLaunchKernelGGL(lstm_main, dim3(256), dim3(512), 0, stream,
                       w1p, w0p, xh, bufA, bufB, hbF, c0,
                       bih0, bhh0, bih1, bhh1, Wout, bout, out, sync);
}